// Round 8
// baseline (105.900 us; speedup 1.0000x reference)
//
#include <hip/hip_runtime.h>
#include <math.h>

#define NN 8192
#define JT 256                         // j-tile width = block size
#define IC 64                          // i-chunk per block
#define NJT (NN / JT)                  // 32 j-tiles
#define NBLOCKS (2 * NJT * (NJT + 1))  // 2112 blocks
#define ALPHA_C 3.0f
#define MIN_DIFF_C 0.1f
#define LOG2E 1.44269504088896340736f
#define LN2   0.69314718055994530942f

// Fused single-dispatch version. Per-block partials are atomicAdd'ed (float,
// device-scope -> cross-XCD coherent) into 4 cacheline-spaced ws slots; the
// last block (float counter, old > NBLOCKS-1.5 — robust to init 0 OR 0xAA
// poison = -3.0e-13f) reads them back with atomic reads and writes out[0].
// No parts array, no memset, no second dispatch. Poison bias on the
// accumulators is -3e-13 — 1e-19 relative to the ~1e7 sums, irrelevant.
// Inner loop identical to R6 (LDS float4 broadcast, XOR sign trick,
// ballot-count on the scalar pipe) — measured spill-free, ~1.5x VALU floor.

#define ACC_S 0     // ws float index: pairwise-loss sum (log2 domain)
#define ACC_C 16    // masked-pair count  (64 B spacing = own cacheline)
#define ACC_R 32    // regression sum
#define ACC_N 48    // completed-block counter

#define PAIR_BODY(PV, TV, VEXTRA)                                          \
    {                                                                      \
        const float dt  = (TV) - tjv;                  /* v_sub */         \
        const float dps = fmaf((PV), LOG2E, npjl);     /* v_fma */         \
        const float xs  = __uint_as_float(__float_as_uint(dps) ^           \
                          (__float_as_uint(dt) & 0x80000000u)); /* and+xor */\
        const float e   = __builtin_amdgcn_exp2f(-xs); /* trans, -mod free */\
        const float lg  = __builtin_amdgcn_logf(1.0f + e); /* add + trans */\
        const bool valid = (VEXTRA) && (fabsf(dt) > MIN_DIFF_C); /* v_cmp */ \
        s = fmaf(valid ? fabsf(dt) : 0.0f, lg, s);     /* cndmask + fma */ \
        cnt += (unsigned int)__popcll(__ballot(valid)); /* SALU */         \
    }

__global__ __launch_bounds__(256, 8) void pair_kernel(
    const float* __restrict__ pred, const float* __restrict__ targ,
    float* __restrict__ acc, float* __restrict__ out) {
    const int b = blockIdx.x;
    // decode b -> (t, ic): blocks before j-tile t = 2*t*(t+1)
    int t = (int)((sqrt(1.0 + 2.0 * (double)b) - 1.0) * 0.5);
    while (2 * (t + 1) * (t + 2) <= b) ++t;
    while (2 * t * (t + 1) > b) --t;
    const int ic = b - 2 * t * (t + 1);
    const int j0 = t * JT;
    const int i0 = ic * IC;

    __shared__ __align__(16) float sP[IC];
    __shared__ __align__(16) float sT[IC];
    const int tid = threadIdx.x;
    if (tid < IC) { sP[tid] = pred[i0 + tid]; sT[tid] = targ[i0 + tid]; }
    __syncthreads();

    const int j = j0 + tid;
    const float pj   = pred[j];
    const float tjv  = targ[j];
    const float npjl = -pj * LOG2E;

    float s = 0.0f;        // sum conf * log2(1+2^-y)   (ln2 applied at end)
    float r = 0.0f;        // regression partial
    unsigned int cnt = 0;  // wave-total masked-pair count (wave-uniform)

    const bool diag  = (ic >= 4 * t);
    const bool owner = (ic == 4 * t + 3);  // carries the MSE term

    if (!diag) {
        #pragma unroll 4
        for (int ii = 0; ii < IC; ii += 4) {
            const float4 p4 = *(const float4*)&sP[ii];  // ds_read_b128
            const float4 t4 = *(const float4*)&sT[ii];  // ds_read_b128
            PAIR_BODY(p4.x, t4.x, true)
            PAIR_BODY(p4.y, t4.y, true)
            PAIR_BODY(p4.z, t4.z, true)
            PAIR_BODY(p4.w, t4.w, true)
        }
    } else {
        #pragma unroll 4
        for (int ii = 0; ii < IC; ii += 4) {
            const float4 p4 = *(const float4*)&sP[ii];
            const float4 t4 = *(const float4*)&sT[ii];
            const int ib = i0 + ii;
            PAIR_BODY(p4.x, t4.x, (ib + 0) < j)
            PAIR_BODY(p4.y, t4.y, (ib + 1) < j)
            PAIR_BODY(p4.z, t4.z, (ib + 2) < j)
            PAIR_BODY(p4.w, t4.w, (ib + 3) < j)
        }
        if (owner) { const float d = pj - tjv; r = d * d; }
    }

    // ---- block reduction: shuffle s,r (64 lanes); cnt is wave-uniform ----
    #pragma unroll
    for (int off = 32; off > 0; off >>= 1) {
        s += __shfl_down(s, off, 64);
        r += __shfl_down(r, off, 64);
    }
    __shared__ float red_s[4], red_c[4], red_r[4];
    const int wave = tid >> 6;
    const int lane = tid & 63;
    if (lane == 0) { red_s[wave] = s; red_c[wave] = (float)cnt; red_r[wave] = r; }
    __syncthreads();

    if (tid == 0) {
        const float fs = red_s[0] + red_s[1] + red_s[2] + red_s[3];
        const float fc = red_c[0] + red_c[1] + red_c[2] + red_c[3];
        atomicAdd(&acc[ACC_S], fs);
        atomicAdd(&acc[ACC_C], fc);
        if (owner) {
            const float fr = red_r[0] + red_r[1] + red_r[2] + red_r[3];
            atomicAdd(&acc[ACC_R], fr);
        }
        __threadfence();  // release: data atomics ordered before the counter
        const float old = atomicAdd(&acc[ACC_N], 1.0f);
        if (old > (float)NBLOCKS - 1.5f) {   // last block to finish
            __threadfence();                 // acquire
            const float S = atomicAdd(&acc[ACC_S], 0.0f);  // coherent reads
            const float C = atomicAdd(&acc[ACC_C], 0.0f);
            const float R = atomicAdd(&acc[ACC_R], 0.0f);
            const float reg = R / (float)NN;
            const float pm  = LN2 * S / fmaxf(C, 1.0f);
            out[0] = (C > 0.5f) ? (reg + ALPHA_C * pm) : reg;
        }
    }
}

extern "C" void kernel_launch(void* const* d_in, const int* in_sizes, int n_in,
                              void* d_out, int out_size, void* d_ws, size_t ws_size,
                              hipStream_t stream) {
    const float* pred = (const float*)d_in[0];
    const float* targ = (const float*)d_in[1];
    float* out = (float*)d_out;
    float* acc = (float*)d_ws;   // 4 float slots, 64 B apart (256 B used)

    pair_kernel<<<NBLOCKS, 256, 0, stream>>>(pred, targ, acc, out);
}

// Round 9
// 70.076 us; speedup vs baseline: 1.5112x; 1.5112x over previous
//
#include <hip/hip_runtime.h>
#include <math.h>

#define NN 8192
#define JT 256                         // j-tile width = block size
#define IC 64                          // i-chunk per block
#define NJT (NN / JT)                  // 32 j-tiles
#define NBLOCKS (2 * NJT * (NJT + 1))  // 2112 blocks
#define ALPHA_C 3.0f
#define MIN_DIFF_C 0.1f
#define LOG2E 1.44269504088896340736f
#define LN2   0.69314718055994530942f

// R6 structure (best measured) + micro-opts. R7 lesson: fused cross-XCD
// atomic+fence reduction serializes on L2 cache maintenance (56 us!) —
// two plain dispatches are far cheaper. Inner loop: LDS float4 broadcast
// (conflict-free), XOR sign trick, ballot-count on the scalar pipe.
// -log_sigmoid(x) = ln2*log2(1+2^(-x*log2e)); ln2 folded into finalize.
// Keep unroll 4: unroll 8 would put ~64 load-VGPRs against the
// launch_bounds(256,8) 64-VGPR cap -> scratch spill (R2: 23 MB WRITE_SIZE).

#define PAIR_BODY(PV, TV, VEXTRA)                                          \
    {                                                                      \
        const float dt  = (TV) - tjv;                  /* v_sub */         \
        const float dps = fmaf((PV), LOG2E, npjl);     /* v_fma */         \
        const float xs  = __uint_as_float(__float_as_uint(dps) ^           \
                          (__float_as_uint(dt) & 0x80000000u)); /* and+xor */\
        const float e   = __builtin_amdgcn_exp2f(-xs); /* trans, -mod free */\
        const float lg  = __builtin_amdgcn_logf(1.0f + e); /* add + trans */\
        const bool valid = (VEXTRA) && (fabsf(dt) > MIN_DIFF_C); /* v_cmp */ \
        s = fmaf(valid ? fabsf(dt) : 0.0f, lg, s);     /* cndmask + fma */ \
        cnt += (unsigned int)__popcll(__ballot(valid)); /* SALU */         \
    }

__global__ __launch_bounds__(256, 8) void pair_kernel(
    const float* __restrict__ pred, const float* __restrict__ targ,
    float4* __restrict__ parts) {
    const int b = blockIdx.x;
    // decode b -> (t, ic): blocks before j-tile t = 2*t*(t+1)
    int t = (int)((sqrt(1.0 + 2.0 * (double)b) - 1.0) * 0.5);
    while (2 * (t + 1) * (t + 2) <= b) ++t;
    while (2 * t * (t + 1) > b) --t;
    const int ic = b - 2 * t * (t + 1);
    const int j0 = t * JT;
    const int i0 = ic * IC;
    const int tid = threadIdx.x;
    const int j = j0 + tid;

    // issue ALL global loads first so their latency overlaps the barrier
    const float pj  = pred[j];
    const float tjv = targ[j];
    float stage_p = 0.0f, stage_t = 0.0f;
    if (tid < IC) { stage_p = pred[i0 + tid]; stage_t = targ[i0 + tid]; }

    __shared__ __align__(16) float sP[IC];
    __shared__ __align__(16) float sT[IC];
    if (tid < IC) { sP[tid] = stage_p; sT[tid] = stage_t; }
    __syncthreads();

    const float npjl = -pj * LOG2E;

    float s = 0.0f;        // sum conf * log2(1+2^-y)   (ln2 applied later)
    float r = 0.0f;        // regression partial
    unsigned int cnt = 0;  // wave-total masked-pair count (wave-uniform)

    const bool diag = (ic >= 4 * t);

    if (!diag) {
        #pragma unroll 4
        for (int ii = 0; ii < IC; ii += 4) {
            const float4 p4 = *(const float4*)&sP[ii];  // ds_read_b128
            const float4 t4 = *(const float4*)&sT[ii];  // ds_read_b128
            PAIR_BODY(p4.x, t4.x, true)
            PAIR_BODY(p4.y, t4.y, true)
            PAIR_BODY(p4.z, t4.z, true)
            PAIR_BODY(p4.w, t4.w, true)
        }
    } else {
        #pragma unroll 4
        for (int ii = 0; ii < IC; ii += 4) {
            const float4 p4 = *(const float4*)&sP[ii];
            const float4 t4 = *(const float4*)&sT[ii];
            const int ib = i0 + ii;
            PAIR_BODY(p4.x, t4.x, (ib + 0) < j)
            PAIR_BODY(p4.y, t4.y, (ib + 1) < j)
            PAIR_BODY(p4.z, t4.z, (ib + 2) < j)
            PAIR_BODY(p4.w, t4.w, (ib + 3) < j)
        }
        // exactly one diagonal chunk per j-tile carries the MSE term
        if (ic == 4 * t + 3) { const float d = pj - tjv; r = d * d; }
    }

    // ---- block reduction: shuffle s (and r only on diag blocks) ----
    #pragma unroll
    for (int off = 32; off > 0; off >>= 1) s += __shfl_down(s, off, 64);
    if (diag) {
        #pragma unroll
        for (int off = 32; off > 0; off >>= 1) r += __shfl_down(r, off, 64);
    }
    __shared__ float red_s[4], red_c[4], red_r[4];
    const int wave = tid >> 6;
    const int lane = tid & 63;
    if (lane == 0) { red_s[wave] = s; red_c[wave] = (float)cnt; red_r[wave] = r; }
    __syncthreads();
    if (tid == 0) {
        parts[b] = make_float4(red_s[0] + red_s[1] + red_s[2] + red_s[3],
                               red_c[0] + red_c[1] + red_c[2] + red_c[3],
                               red_r[0] + red_r[1] + red_r[2] + red_r[3], 0.0f);
    }
}

__global__ __launch_bounds__(256) void finalize_kernel(
    const float4* __restrict__ parts, float* __restrict__ out) {
    float s = 0.0f, c = 0.0f, r = 0.0f;
    for (int i = threadIdx.x; i < NBLOCKS; i += 256) {
        const float4 v = parts[i];
        s += v.x; c += v.y; r += v.z;
    }
    #pragma unroll
    for (int off = 32; off > 0; off >>= 1) {
        s += __shfl_down(s, off, 64);
        c += __shfl_down(c, off, 64);
        r += __shfl_down(r, off, 64);
    }
    __shared__ float red_s[4], red_c[4], red_r[4];
    const int wave = threadIdx.x >> 6;
    const int lane = threadIdx.x & 63;
    if (lane == 0) { red_s[wave] = s; red_c[wave] = c; red_r[wave] = r; }
    __syncthreads();
    if (threadIdx.x == 0) {
        const float fs = red_s[0] + red_s[1] + red_s[2] + red_s[3];
        const float fc = red_c[0] + red_c[1] + red_c[2] + red_c[3];
        const float fr = red_r[0] + red_r[1] + red_r[2] + red_r[3];
        const float reg = fr / (float)NN;
        const float pm  = LN2 * fs / fmaxf(fc, 1.0f);
        out[0] = (fc > 0.0f) ? (reg + ALPHA_C * pm) : reg;
    }
}

extern "C" void kernel_launch(void* const* d_in, const int* in_sizes, int n_in,
                              void* d_out, int out_size, void* d_ws, size_t ws_size,
                              hipStream_t stream) {
    const float* pred = (const float*)d_in[0];
    const float* targ = (const float*)d_in[1];
    float* out = (float*)d_out;
    float4* parts = (float4*)d_ws;   // NBLOCKS * 16 B = 33,792 B

    pair_kernel<<<NBLOCKS, 256, 0, stream>>>(pred, targ, parts);
    finalize_kernel<<<1, 256, 0, stream>>>(parts, out);
}